// Round 4
// baseline (220.656 us; speedup 1.0000x reference)
//
#include <hip/hip_runtime.h>
#include <hip/hip_bf16.h>
#include <stdint.h>
#include <stddef.h>

#define TM 16      // output rows per block
#define CIN 64     // C_in
#define NK3 27     // K3 neighbors
#define COUT 128   // C_out
#define EPS_LN 1e-3f

__global__ __launch_bounds__(256) void dpc_fused(
    const float* __restrict__ features,   // fp32 [N][CIN]
    const float* __restrict__ center,     // fp32 [M][3]
    const int* __restrict__ voxel_idx,    // int32 or int64 [M][NK3] (auto-detected)
    const int* __restrict__ num_list,     // int32 or int64 [B]     (auto-detected)
    const float* __restrict__ Wm,         // fp32 [NK3*CIN][COUT]
    const float* __restrict__ gamma_,     // fp32 [COUT]
    const float* __restrict__ beta_,      // fp32 [COUT]
    float* __restrict__ out_feat,         // fp32 [Rtot][COUT]
    float* __restrict__ out_coor,         // fp32 [Rtot][4]
    int N, int M, int B, int K, int Rtot)
{
    __shared__ int   s_flags;        // bit0: voxel_idx is int64, bit1: num_list is int64
    __shared__ int   s_vid[TM][NK3];
    __shared__ int   s_src[TM];
    __shared__ int   s_valid[TM];
    __shared__ float s_a[TM][CIN];   // gathered fp32 tile for current k3 chunk

    const int t  = threadIdx.x;
    const int R0 = blockIdx.x * TM;

    // ---- dtype probe: int64 arrays have zero high words (values < 2^31) ----
    if (t == 0) {
        int f = 0;
        bool v64 = true;
        for (int j = 1; j < 128; j += 2) {
            if (voxel_idx[j] != 0) { v64 = false; break; }
        }
        if (v64) f |= 1;
        bool n64 = false;
        if (B >= 2) {
            n64 = (num_list[1] == 0) && (num_list[0] != 0);
            if (B >= 4) n64 = n64 && (num_list[3] == 0);
        }
        if (n64) f |= 2;
        s_flags = f;
    }
    __syncthreads();
    const bool vidx64 = (s_flags & 1) != 0;
    const bool nl64   = (s_flags & 2) != 0;

    // ---- preamble: per-row source index + validity from num_list ----
    if (t < TM) {
        int r = R0 + t;
        int src = 0, valid = 0;
        if (r < Rtot) {
            int b = r / K;
            int j = r - b * K;
            int offs = 0, nlb = 0;
            for (int i = 0; i < B; ++i) {
                int v = nl64 ? num_list[2 * i] : num_list[i];
                if (i < b) offs += v;
                if (i == b) nlb = v;
            }
            int end = nlb < K ? nlb : K;
            valid = (j < end) ? 1 : 0;
            src = offs + j;
            if (src < 0) src = 0;
            if (src > M - 1) src = M - 1;
        }
        s_src[t] = src;
        s_valid[t] = valid;
    }
    __syncthreads();

    // ---- coords output: [col0, x, y, z] per row ----
    if (t < TM * 4) {
        int i = t >> 2, comp = t & 3;
        int r = R0 + i;
        if (r < Rtot) {
            float val;
            if (comp == 0) {
                int b = r / K;
                val = (b < B - 1) ? (float)(b + 1) : 0.0f;   // reference's quirk
            } else {
                val = s_valid[i] ? center[(size_t)s_src[i] * 3 + comp - 1] : 0.0f;
            }
            out_coor[(size_t)r * 4 + comp] = val;
        }
    }

    // ---- stage voxel ids (16 rows x 27) ----
    for (int lin = t; lin < TM * NK3; lin += 256) {
        int i = lin / NK3;
        int k = lin - i * NK3;
        size_t e = (size_t)s_src[i] * NK3 + k;
        s_vid[i][k] = vidx64 ? voxel_idx[2 * e] : voxel_idx[e];
    }
    // (first __syncthreads in the chunk loop covers this)

    const int h  = t >> 6;          // wave id 0..3 -> owns rows h*4 .. h*4+3
    const int c2 = (t & 63) * 2;    // column pair base: 0,2,...,126

    float acc0[4], acc1[4];
    #pragma unroll
    for (int i = 0; i < 4; ++i) { acc0[i] = 0.f; acc1[i] = 0.f; }

    for (int kc = 0; kc < NK3; ++kc) {
        __syncthreads();   // protect s_a (and s_vid on iter 0)
        // stage gathered 16x64 fp32 -> LDS (coalesced per row)
        #pragma unroll
        for (int rep = 0; rep < 4; ++rep) {
            int lin = rep * 256 + t;       // element index 0..1023
            int i = lin >> 6;              // row 0..15
            int c = lin & 63;              // cin 0..63
            int idx = s_vid[i][kc];
            float v = 0.f;
            if (idx >= 0) {                // negative idx -> padding 0
                if (idx > N - 1) idx = N - 1;
                v = features[(size_t)idx * CIN + c];
            }
            s_a[i][c] = v;
        }
        __syncthreads();

        const float* wp = Wm + (size_t)kc * CIN * COUT + c2;
        #pragma unroll 8
        for (int e = 0; e < CIN; ++e) {
            float w0 = wp[(size_t)e * COUT];
            float w1 = wp[(size_t)e * COUT + 1];
            #pragma unroll
            for (int i = 0; i < 4; ++i) {
                float a = s_a[h * 4 + i][e];   // wave-uniform broadcast
                acc0[i] = fmaf(a, w0, acc0[i]);
                acc1[i] = fmaf(a, w1, acc1[i]);
            }
        }
    }

    // ---- fused LayerNorm + ReLU epilogue (each wave holds complete rows) ----
    const float g0  = gamma_[c2];
    const float g1  = gamma_[c2 + 1];
    const float be0 = beta_[c2];
    const float be1 = beta_[c2 + 1];

    #pragma unroll
    for (int i = 0; i < 4; ++i) {
        int row = h * 4 + i;
        float s  = acc0[i] + acc1[i];
        float ss = acc0[i] * acc0[i] + acc1[i] * acc1[i];
        #pragma unroll
        for (int m = 1; m < 64; m <<= 1) {   // 64-lane butterfly
            s  += __shfl_xor(s,  m, 64);
            ss += __shfl_xor(ss, m, 64);
        }
        float mu   = s * (1.0f / COUT);
        float var  = ss * (1.0f / COUT) - mu * mu;
        float rstd = rsqrtf(var + EPS_LN);
        float v0 = (acc0[i] - mu) * rstd * g0 + be0;
        float v1 = (acc1[i] - mu) * rstd * g1 + be1;
        v0 = fmaxf(v0, 0.f);
        v1 = fmaxf(v1, 0.f);
        if (!s_valid[row]) { v0 = 0.f; v1 = 0.f; }
        int r = R0 + row;
        if (r < Rtot) {
            out_feat[(size_t)r * COUT + c2]     = v0;
            out_feat[(size_t)r * COUT + c2 + 1] = v1;
        }
    }
}

extern "C" void kernel_launch(void* const* d_in, const int* in_sizes, int n_in,
                              void* d_out, int out_size, void* d_ws, size_t ws_size,
                              hipStream_t stream) {
    const float* features = (const float*)d_in[0];
    const float* center   = (const float*)d_in[1];
    const int*   vidx     = (const int*)d_in[2];
    const int*   num_list = (const int*)d_in[3];
    const float* Wm       = (const float*)d_in[4];
    const float* gamma_   = (const float*)d_in[5];
    const float* beta_    = (const float*)d_in[6];

    const int B    = in_sizes[3];                 // 4
    const int Cout = in_sizes[5];                 // 128
    const int M    = in_sizes[1] / 3;             // 40000
    const int K3v  = in_sizes[2] / M;             // 27
    const int Cin  = (in_sizes[4] / Cout) / K3v;  // 64
    const int N    = in_sizes[0] / Cin;           // 200000
    const int Rtot = out_size / (Cout + 4);       // 8192
    const int K    = Rtot / B;                    // 2048

    float* out_feat = (float*)d_out;
    float* out_coor = out_feat + (size_t)Rtot * Cout;

    const int grid = (Rtot + TM - 1) / TM;        // 512
    dpc_fused<<<dim3(grid), dim3(256), 0, stream>>>(
        features, center, vidx, num_list, Wm, gamma_, beta_,
        out_feat, out_coor, N, M, B, K, Rtot);
}

// Round 5
// 114.983 us; speedup vs baseline: 1.9190x; 1.9190x over previous
//
#include <hip/hip_runtime.h>
#include <hip/hip_bf16.h>
#include <stdint.h>
#include <stddef.h>

#define TM 16      // output rows per block
#define CIN 64     // C_in
#define NK3 27     // K3 neighbors
#define COUT 128   // C_out
#define EPS_LN 1e-3f
#define KCH (NK3 * CIN / 32)   // 54 k-chunks of 32
#define NT  (COUT / 16)        // 8 column tiles

typedef __attribute__((ext_vector_type(8))) short   short8;   // 8 bf16 = 4 VGPRs (MFMA A/B frag)
typedef __attribute__((ext_vector_type(4))) float   floatx4;  // MFMA C/D frag
typedef __attribute__((ext_vector_type(4))) unsigned short ushort4v;

__device__ __forceinline__ unsigned short f2b(float f) {
    union { float f; unsigned int i; } v;
    v.f = f;
    unsigned int i = v.i; // round-to-nearest-even bf16
    return (unsigned short)((i + 0x7fffu + ((i >> 16) & 1u)) >> 16);
}

// ---- kernel 1: pack W fp32 -> bf16 in MFMA B-fragment order ----
// packed[((nt*KCH + kk)*64 + lane)*8 + j] = bf16( W[(kk*32 + (lane>>4)*8 + j)*COUT + nt*16 + (lane&15)] )
__global__ __launch_bounds__(256) void pack_w(const float* __restrict__ Wm,
                                              unsigned short* __restrict__ pk) {
    int slot = blockIdx.x * 256 + threadIdx.x;   // 0 .. NT*KCH*64-1 (= 27648)
    int l  = slot & 63;
    int kk = (slot >> 6) % KCH;
    int nt = slot / (64 * KCH);
    int q = l >> 4, n = l & 15;
    const float* src = Wm + (size_t)(kk * 32 + q * 8) * COUT + nt * 16 + n;
    short8 v;
    #pragma unroll
    for (int j = 0; j < 8; ++j)
        v[j] = (short)f2b(src[(size_t)j * COUT]);
    *(short8*)(pk + (size_t)slot * 8) = v;
}

// ---- kernel 2: fused gather + bf16 MFMA GEMM + LayerNorm + ReLU + resample ----
__global__ __launch_bounds__(256) void dpc_mfma(
    const float* __restrict__ features,   // fp32 [N][CIN]
    const float* __restrict__ center,     // fp32 [M][3]
    const int* __restrict__ voxel_idx,    // int32/int64 (probed) [M][NK3]
    const int* __restrict__ num_list,     // int32/int64 (probed) [B]
    const unsigned short* __restrict__ pk,// bf16 packed W fragments
    const float* __restrict__ gamma_,     // fp32 [COUT]
    const float* __restrict__ beta_,      // fp32 [COUT]
    float* __restrict__ out_feat,         // fp32 [Rtot][COUT]
    float* __restrict__ out_coor,         // fp32 [Rtot][4]
    int N, int M, int B, int K, int Rtot)
{
    __shared__ int s_flags;
    __shared__ int s_vid[TM][NK3];
    __shared__ int s_src[TM];
    __shared__ int s_valid[TM];
    __shared__ __align__(16) unsigned short s_a[2][1024]; // [dbuf][chunk*512 + lane*8 + j] (A-frag order)
    __shared__ float s_c[TM][COUT + 4];                   // +4 pad -> 2-way (free) on C scatter

    const int t  = threadIdx.x;
    const int R0 = blockIdx.x * TM;

    // ---- dtype probe (verified round 4): int64 arrays have zero high words ----
    if (t == 0) {
        int f = 0;
        bool v64 = true;
        for (int j = 1; j < 128; j += 2) {
            if (voxel_idx[j] != 0) { v64 = false; break; }
        }
        if (v64) f |= 1;
        bool n64 = false;
        if (B >= 2) {
            n64 = (num_list[1] == 0) && (num_list[0] != 0);
            if (B >= 4) n64 = n64 && (num_list[3] == 0);
        }
        if (n64) f |= 2;
        s_flags = f;
    }
    __syncthreads();
    const bool vidx64 = (s_flags & 1) != 0;
    const bool nl64   = (s_flags & 2) != 0;

    // ---- preamble: per-row source index + validity ----
    if (t < TM) {
        int r = R0 + t;
        int src = 0, valid = 0;
        if (r < Rtot) {
            int b = r / K;
            int j = r - b * K;
            int offs = 0, nlb = 0;
            for (int i = 0; i < B; ++i) {
                int v = nl64 ? num_list[2 * i] : num_list[i];
                if (i < b) offs += v;
                if (i == b) nlb = v;
            }
            int end = nlb < K ? nlb : K;
            valid = (j < end) ? 1 : 0;
            src = offs + j;
            if (src < 0) src = 0;
            if (src > M - 1) src = M - 1;
        }
        s_src[t] = src;
        s_valid[t] = valid;
    }
    __syncthreads();

    // ---- coords output ----
    if (t < TM * 4) {
        int i = t >> 2, comp = t & 3;
        int r = R0 + i;
        if (r < Rtot) {
            float val;
            if (comp == 0) {
                int b = r / K;
                val = (b < B - 1) ? (float)(b + 1) : 0.0f;
            } else {
                val = s_valid[i] ? center[(size_t)s_src[i] * 3 + comp - 1] : 0.0f;
            }
            out_coor[(size_t)r * 4 + comp] = val;
        }
    }

    // ---- stage voxel ids ----
    for (int lin = t; lin < TM * NK3; lin += 256) {
        int i = lin / NK3;
        int k = lin - i * NK3;
        size_t e = (size_t)s_src[i] * NK3 + k;
        s_vid[i][k] = vidx64 ? voxel_idx[2 * e] : voxel_idx[e];
    }
    __syncthreads();

    // ---- staging geometry: thread t gathers float4 (row m, cols c0..c0+3) ----
    const int m  = t >> 4;            // row 0..15
    const int c0 = (t & 15) * 4;      // cin col base
    const int chunk = c0 >> 5;        // which 32-wide k-chunk of this kc
    const int q4    = (c0 & 31) >> 3; // quad
    const int j0    = c0 & 7;         // 0 or 4
    const int aoff  = chunk * 512 + (q4 * 16 + m) * 8 + j0;  // ushort index in s_a[buf]

    auto gatherf4 = [&](int kc) -> float4 {
        int idx = s_vid[m][kc];
        float4 r = make_float4(0.f, 0.f, 0.f, 0.f);
        if (idx >= 0) {
            if (idx > N - 1) idx = N - 1;
            r = *(const float4*)(features + (size_t)idx * CIN + c0);
        }
        return r;
    };
    auto stash = [&](int buf, float4 v) {
        ushort4v u;
        u[0] = f2b(v.x); u[1] = f2b(v.y); u[2] = f2b(v.z); u[3] = f2b(v.w);
        *(ushort4v*)&s_a[buf][aoff] = u;
    };

    const int w    = t >> 6;          // wave 0..3 -> col tiles 2w, 2w+1
    const int lane = t & 63;
    const int nt0 = 2 * w, nt1 = 2 * w + 1;

    floatx4 acc0 = {0.f, 0.f, 0.f, 0.f};
    floatx4 acc1 = {0.f, 0.f, 0.f, 0.f};

    stash(0, gatherf4(0));
    __syncthreads();

    for (int kc = 0; kc < NK3; ++kc) {
        float4 pref;
        const bool hn = (kc + 1 < NK3);
        if (hn) pref = gatherf4(kc + 1);          // prefetch next gather (overlaps compute)

        const int kk0 = kc * 2;
        const int buf = kc & 1;
        // B fragments: coalesced 16B/lane from packed W (L2-resident)
        const short8 b00 = *(const short8*)(pk + ((size_t)(nt0 * KCH + kk0    ) * 64 + lane) * 8);
        const short8 b01 = *(const short8*)(pk + ((size_t)(nt0 * KCH + kk0 + 1) * 64 + lane) * 8);
        const short8 b10 = *(const short8*)(pk + ((size_t)(nt1 * KCH + kk0    ) * 64 + lane) * 8);
        const short8 b11 = *(const short8*)(pk + ((size_t)(nt1 * KCH + kk0 + 1) * 64 + lane) * 8);
        // A fragments: conflict-free ds_read_b128 (fragment-ordered staging)
        const short8 a0 = *(const short8*)&s_a[buf][lane * 8];
        const short8 a1 = *(const short8*)&s_a[buf][512 + lane * 8];

        acc0 = __builtin_amdgcn_mfma_f32_16x16x32_bf16(a0, b00, acc0, 0, 0, 0);
        acc0 = __builtin_amdgcn_mfma_f32_16x16x32_bf16(a1, b01, acc0, 0, 0, 0);
        acc1 = __builtin_amdgcn_mfma_f32_16x16x32_bf16(a0, b10, acc1, 0, 0, 0);
        acc1 = __builtin_amdgcn_mfma_f32_16x16x32_bf16(a1, b11, acc1, 0, 0, 0);

        if (hn) stash((kc + 1) & 1, pref);        // write other buffer
        __syncthreads();
    }

    // ---- C fragments -> LDS (C/D layout: col=lane&15, row=(lane>>4)*4+reg; m89-verified) ----
    {
        const int q = lane >> 4, n = lane & 15;
        #pragma unroll
        for (int reg = 0; reg < 4; ++reg) {
            s_c[q * 4 + reg][nt0 * 16 + n] = acc0[reg];
            s_c[q * 4 + reg][nt1 * 16 + n] = acc1[reg];
        }
    }
    __syncthreads();

    // ---- fused LayerNorm + ReLU epilogue (verified round 4, fed from s_c) ----
    const int h  = t >> 6;
    const int c2 = (t & 63) * 2;
    const float g0  = gamma_[c2];
    const float g1  = gamma_[c2 + 1];
    const float be0 = beta_[c2];
    const float be1 = beta_[c2 + 1];

    #pragma unroll
    for (int i = 0; i < 4; ++i) {
        int row = h * 4 + i;
        float a0 = s_c[row][c2];
        float a1 = s_c[row][c2 + 1];
        float s  = a0 + a1;
        float ss = a0 * a0 + a1 * a1;
        #pragma unroll
        for (int mm = 1; mm < 64; mm <<= 1) {   // 64-lane butterfly
            s  += __shfl_xor(s,  mm, 64);
            ss += __shfl_xor(ss, mm, 64);
        }
        float mu   = s * (1.0f / COUT);
        float var  = ss * (1.0f / COUT) - mu * mu;
        float rstd = rsqrtf(var + EPS_LN);
        float v0 = (a0 - mu) * rstd * g0 + be0;
        float v1 = (a1 - mu) * rstd * g1 + be1;
        v0 = fmaxf(v0, 0.f);
        v1 = fmaxf(v1, 0.f);
        if (!s_valid[row]) { v0 = 0.f; v1 = 0.f; }
        int r = R0 + row;
        if (r < Rtot) {
            out_feat[(size_t)r * COUT + c2]     = v0;
            out_feat[(size_t)r * COUT + c2 + 1] = v1;
        }
    }
}

extern "C" void kernel_launch(void* const* d_in, const int* in_sizes, int n_in,
                              void* d_out, int out_size, void* d_ws, size_t ws_size,
                              hipStream_t stream) {
    const float* features = (const float*)d_in[0];
    const float* center   = (const float*)d_in[1];
    const int*   vidx     = (const int*)d_in[2];
    const int*   num_list = (const int*)d_in[3];
    const float* Wm       = (const float*)d_in[4];
    const float* gamma_   = (const float*)d_in[5];
    const float* beta_    = (const float*)d_in[6];

    const int B    = in_sizes[3];                 // 4
    const int Cout = in_sizes[5];                 // 128
    const int M    = in_sizes[1] / 3;             // 40000
    const int K3v  = in_sizes[2] / M;             // 27
    const int Cin  = (in_sizes[4] / Cout) / K3v;  // 64
    const int N    = in_sizes[0] / Cin;           // 200000
    const int Rtot = out_size / (Cout + 4);       // 8192
    const int K    = Rtot / B;                    // 2048

    float* out_feat = (float*)d_out;
    float* out_coor = out_feat + (size_t)Rtot * Cout;
    unsigned short* pk = (unsigned short*)d_ws;   // needs NT*KCH*64*8*2 = 442368 B

    const int pack_grid = (NT * KCH * 64) / 256;  // 108
    pack_w<<<dim3(pack_grid), dim3(256), 0, stream>>>(Wm, pk);

    const int grid = (Rtot + TM - 1) / TM;        // 512
    dpc_mfma<<<dim3(grid), dim3(256), 0, stream>>>(
        features, center, vidx, num_list, pk, gamma_, beta_,
        out_feat, out_coor, N, M, B, K, Rtot);
}

// Round 6
// 113.216 us; speedup vs baseline: 1.9490x; 1.0156x over previous
//
#include <hip/hip_runtime.h>
#include <hip/hip_bf16.h>
#include <stdint.h>
#include <stddef.h>

#define TM 16      // output rows per block
#define CIN 64     // C_in
#define NK3 27     // K3 neighbors
#define NK3P 28    // padded to even (kc=27 is all-zero)
#define COUT 128   // C_out
#define EPS_LN 1e-3f
#define KCH  (NK3 * CIN / 32)    // 54 real k-chunks of 32
#define KCHP (NK3P * CIN / 32)   // 56 padded k-chunks
#define NT   (COUT / 16)         // 8 column tiles
#define NPAIR (NK3P / 2)         // 14 kc-pairs

typedef __attribute__((ext_vector_type(8))) short   short8;   // 8 bf16 = 4 VGPRs (MFMA A/B frag)
typedef __attribute__((ext_vector_type(4))) float   floatx4;  // MFMA C/D frag
typedef __attribute__((ext_vector_type(4))) unsigned short ushort4v;

__device__ __forceinline__ unsigned short f2b(float f) {
    union { float f; unsigned int i; } v;
    v.f = f;
    unsigned int i = v.i; // round-to-nearest-even bf16
    return (unsigned short)((i + 0x7fffu + ((i >> 16) & 1u)) >> 16);
}

// ---- kernel 1: pack W fp32 -> bf16 in MFMA B-fragment order (padded with zero chunks) ----
__global__ __launch_bounds__(256) void pack_w(const float* __restrict__ Wm,
                                              unsigned short* __restrict__ pk) {
    int slot = blockIdx.x * 256 + threadIdx.x;   // 0 .. NT*KCHP*64-1 (= 28671)
    int l  = slot & 63;
    int kk = (slot >> 6) % KCHP;
    int nt = slot / (64 * KCHP);
    short8 v = {0, 0, 0, 0, 0, 0, 0, 0};
    if (kk < KCH) {
        int q = l >> 4, n = l & 15;
        const float* src = Wm + (size_t)(kk * 32 + q * 8) * COUT + nt * 16 + n;
        #pragma unroll
        for (int j = 0; j < 8; ++j)
            v[j] = (short)f2b(src[(size_t)j * COUT]);
    }
    *(short8*)(pk + (size_t)slot * 8) = v;
}

// ---- kernel 2: fused gather + bf16 MFMA GEMM + LayerNorm + ReLU + resample ----
__global__ __launch_bounds__(256) void dpc_mfma(
    const float* __restrict__ features,   // fp32 [N][CIN]
    const float* __restrict__ center,     // fp32 [M][3]
    const int* __restrict__ voxel_idx,    // int32/int64 (probed) [M][NK3]
    const int* __restrict__ num_list,     // int32/int64 (probed) [B]
    const unsigned short* __restrict__ pk,// bf16 packed W fragments (KCHP chunks)
    const float* __restrict__ gamma_,     // fp32 [COUT]
    const float* __restrict__ beta_,      // fp32 [COUT]
    float* __restrict__ out_feat,         // fp32 [Rtot][COUT]
    float* __restrict__ out_coor,         // fp32 [Rtot][4]
    int N, int M, int B, int K, int Rtot)
{
    __shared__ int s_flags;
    __shared__ int s_vid[TM][NK3P];
    __shared__ int s_src[TM];
    __shared__ int s_valid[TM];
    __shared__ __align__(16) unsigned short s_a[2][2048]; // [pair dbuf][sub*1024 + chunk*512 + frag]
    __shared__ float s_c[TM][COUT + 4];                   // +4 pad on C scatter

    const int t  = threadIdx.x;
    const int R0 = blockIdx.x * TM;

    // ---- dtype probe (verified round 4): int64 arrays have zero high words ----
    if (t == 0) {
        int f = 0;
        bool v64 = true;
        for (int j = 1; j < 128; j += 2) {
            if (voxel_idx[j] != 0) { v64 = false; break; }
        }
        if (v64) f |= 1;
        bool n64 = false;
        if (B >= 2) {
            n64 = (num_list[1] == 0) && (num_list[0] != 0);
            if (B >= 4) n64 = n64 && (num_list[3] == 0);
        }
        if (n64) f |= 2;
        s_flags = f;
    }
    __syncthreads();
    const bool vidx64 = (s_flags & 1) != 0;
    const bool nl64   = (s_flags & 2) != 0;

    // ---- preamble: per-row source index + validity ----
    if (t < TM) {
        int r = R0 + t;
        int src = 0, valid = 0;
        if (r < Rtot) {
            int b = r / K;
            int j = r - b * K;
            int offs = 0, nlb = 0;
            for (int i = 0; i < B; ++i) {
                int v = nl64 ? num_list[2 * i] : num_list[i];
                if (i < b) offs += v;
                if (i == b) nlb = v;
            }
            int end = nlb < K ? nlb : K;
            valid = (j < end) ? 1 : 0;
            src = offs + j;
            if (src < 0) src = 0;
            if (src > M - 1) src = M - 1;
        }
        s_src[t] = src;
        s_valid[t] = valid;
    }
    __syncthreads();

    // ---- coords output ----
    if (t < TM * 4) {
        int i = t >> 2, comp = t & 3;
        int r = R0 + i;
        if (r < Rtot) {
            float val;
            if (comp == 0) {
                int b = r / K;
                val = (b < B - 1) ? (float)(b + 1) : 0.0f;
            } else {
                val = s_valid[i] ? center[(size_t)s_src[i] * 3 + comp - 1] : 0.0f;
            }
            out_coor[(size_t)r * 4 + comp] = val;
        }
    }

    // ---- stage voxel ids (pad kc=27 with -1 -> zero A fragment) ----
    for (int lin = t; lin < TM * NK3P; lin += 256) {
        int i = lin / NK3P;
        int k = lin - i * NK3P;
        int v = -1;
        if (k < NK3) {
            size_t e = (size_t)s_src[i] * NK3 + k;
            v = vidx64 ? voxel_idx[2 * e] : voxel_idx[e];
        }
        s_vid[i][k] = v;
    }
    __syncthreads();

    // ---- staging geometry: thread t gathers float4 (row m, cols c0..c0+3) ----
    const int m  = t >> 4;            // row 0..15
    const int c0 = (t & 15) * 4;      // cin col base
    const int chunk = c0 >> 5;        // which 32-wide k-chunk of this kc
    const int q4    = (c0 & 31) >> 3; // quad
    const int j0    = c0 & 7;         // 0 or 4
    const int aoff  = chunk * 512 + (q4 * 16 + m) * 8 + j0;  // ushort index within a kc slab

    auto gatherf4 = [&](int kc) -> float4 {
        int idx = s_vid[m][kc];
        float4 r = make_float4(0.f, 0.f, 0.f, 0.f);
        if (idx >= 0) {
            if (idx > N - 1) idx = N - 1;
            r = *(const float4*)(features + (size_t)idx * CIN + c0);
        }
        return r;
    };
    auto stash = [&](int buf, int sub, float4 v) {
        ushort4v u;
        u[0] = f2b(v.x); u[1] = f2b(v.y); u[2] = f2b(v.z); u[3] = f2b(v.w);
        *(ushort4v*)&s_a[buf][sub * 1024 + aoff] = u;
    };

    const int w    = t >> 6;          // wave 0..3 -> col tiles 2w, 2w+1
    const int lane = t & 63;
    const int nt0 = 2 * w, nt1 = 2 * w + 1;

    auto loadB = [&](int nt, int kk) -> short8 {
        return *(const short8*)(pk + ((size_t)(nt * KCHP + kk) * 64 + lane) * 8);
    };

    floatx4 acc0 = {0.f, 0.f, 0.f, 0.f};
    floatx4 acc1 = {0.f, 0.f, 0.f, 0.f};

    // prologue: stage pair 0, preload B for pair 0
    stash(0, 0, gatherf4(0));
    stash(0, 1, gatherf4(1));
    short8 bb[8];
    #pragma unroll
    for (int c = 0; c < 4; ++c) {
        bb[2 * c]     = loadB(nt0, c);
        bb[2 * c + 1] = loadB(nt1, c);
    }
    __syncthreads();

    for (int p = 0; p < NPAIR; ++p) {
        const int  buf = p & 1;
        const bool hn  = (p + 1 < NPAIR);

        // prefetch gathers for pair p+1 (distance = 2 kc; covers LLC latency)
        float4 n0, n1;
        if (hn) { n0 = gatherf4(2 * p + 2); n1 = gatherf4(2 * p + 3); }
        // register-pipeline B for pair p+1 (L2 latency overlaps MFMAs below)
        short8 nb[8];
        if (hn) {
            #pragma unroll
            for (int c = 0; c < 4; ++c) {
                nb[2 * c]     = loadB(nt0, 4 * (p + 1) + c);
                nb[2 * c + 1] = loadB(nt1, 4 * (p + 1) + c);
            }
        }

        // A fragments: conflict-free ds_read_b128 (fragment-ordered staging)
        const short8 a0 = *(const short8*)&s_a[buf][           lane * 8];
        const short8 a1 = *(const short8*)&s_a[buf][ 512 +     lane * 8];
        const short8 a2 = *(const short8*)&s_a[buf][1024 +     lane * 8];
        const short8 a3 = *(const short8*)&s_a[buf][1536 +     lane * 8];

        acc0 = __builtin_amdgcn_mfma_f32_16x16x32_bf16(a0, bb[0], acc0, 0, 0, 0);
        acc1 = __builtin_amdgcn_mfma_f32_16x16x32_bf16(a0, bb[1], acc1, 0, 0, 0);
        acc0 = __builtin_amdgcn_mfma_f32_16x16x32_bf16(a1, bb[2], acc0, 0, 0, 0);
        acc1 = __builtin_amdgcn_mfma_f32_16x16x32_bf16(a1, bb[3], acc1, 0, 0, 0);
        acc0 = __builtin_amdgcn_mfma_f32_16x16x32_bf16(a2, bb[4], acc0, 0, 0, 0);
        acc1 = __builtin_amdgcn_mfma_f32_16x16x32_bf16(a2, bb[5], acc1, 0, 0, 0);
        acc0 = __builtin_amdgcn_mfma_f32_16x16x32_bf16(a3, bb[6], acc0, 0, 0, 0);
        acc1 = __builtin_amdgcn_mfma_f32_16x16x32_bf16(a3, bb[7], acc1, 0, 0, 0);

        if (hn) {
            stash(buf ^ 1, 0, n0);
            stash(buf ^ 1, 1, n1);
        }
        __syncthreads();
        if (hn) {
            #pragma unroll
            for (int i = 0; i < 8; ++i) bb[i] = nb[i];
        }
    }

    // ---- C fragments -> LDS (C/D layout: col=lane&15, row=(lane>>4)*4+reg) ----
    {
        const int q = lane >> 4, n = lane & 15;
        #pragma unroll
        for (int reg = 0; reg < 4; ++reg) {
            s_c[q * 4 + reg][nt0 * 16 + n] = acc0[reg];
            s_c[q * 4 + reg][nt1 * 16 + n] = acc1[reg];
        }
    }
    __syncthreads();

    // ---- fused LayerNorm + ReLU epilogue ----
    const int h  = t >> 6;
    const int c2 = (t & 63) * 2;
    const float g0  = gamma_[c2];
    const float g1  = gamma_[c2 + 1];
    const float be0 = beta_[c2];
    const float be1 = beta_[c2 + 1];

    #pragma unroll
    for (int i = 0; i < 4; ++i) {
        int row = h * 4 + i;
        float a0 = s_c[row][c2];
        float a1 = s_c[row][c2 + 1];
        float s  = a0 + a1;
        float ss = a0 * a0 + a1 * a1;
        #pragma unroll
        for (int mm = 1; mm < 64; mm <<= 1) {   // 64-lane butterfly
            s  += __shfl_xor(s,  mm, 64);
            ss += __shfl_xor(ss, mm, 64);
        }
        float mu   = s * (1.0f / COUT);
        float var  = ss * (1.0f / COUT) - mu * mu;
        float rstd = rsqrtf(var + EPS_LN);
        float v0 = (a0 - mu) * rstd * g0 + be0;
        float v1 = (a1 - mu) * rstd * g1 + be1;
        v0 = fmaxf(v0, 0.f);
        v1 = fmaxf(v1, 0.f);
        if (!s_valid[row]) { v0 = 0.f; v1 = 0.f; }
        int r = R0 + row;
        if (r < Rtot) {
            out_feat[(size_t)r * COUT + c2]     = v0;
            out_feat[(size_t)r * COUT + c2 + 1] = v1;
        }
    }
}

extern "C" void kernel_launch(void* const* d_in, const int* in_sizes, int n_in,
                              void* d_out, int out_size, void* d_ws, size_t ws_size,
                              hipStream_t stream) {
    const float* features = (const float*)d_in[0];
    const float* center   = (const float*)d_in[1];
    const int*   vidx     = (const int*)d_in[2];
    const int*   num_list = (const int*)d_in[3];
    const float* Wm       = (const float*)d_in[4];
    const float* gamma_   = (const float*)d_in[5];
    const float* beta_    = (const float*)d_in[6];

    const int B    = in_sizes[3];                 // 4
    const int Cout = in_sizes[5];                 // 128
    const int M    = in_sizes[1] / 3;             // 40000
    const int K3v  = in_sizes[2] / M;             // 27
    const int Cin  = (in_sizes[4] / Cout) / K3v;  // 64
    const int N    = in_sizes[0] / Cin;           // 200000
    const int Rtot = out_size / (Cout + 4);       // 8192
    const int K    = Rtot / B;                    // 2048

    float* out_feat = (float*)d_out;
    float* out_coor = out_feat + (size_t)Rtot * Cout;
    unsigned short* pk = (unsigned short*)d_ws;   // needs NT*KCHP*64*8*2 = 458752 B

    const int pack_grid = (NT * KCHP * 64) / 256; // 112
    pack_w<<<dim3(pack_grid), dim3(256), 0, stream>>>(Wm, pk);

    const int grid = (Rtot + TM - 1) / TM;        // 512
    dpc_mfma<<<dim3(grid), dim3(256), 0, stream>>>(
        features, center, vidx, num_list, pk, gamma_, beta_,
        out_feat, out_coor, N, M, B, K, Rtot);
}